// Round 9
// baseline (368.521 us; speedup 1.0000x reference)
//
#include <hip/hip_runtime.h>
#include <hip/hip_fp16.h>
#include <stdint.h>

#define NLEVELS 16
#define BLOCK 256
#define NPT 2

#define P1 2654435761u
#define P2 805459861u
#define HMASK 0x7FFFFu

// ---- dense quad tables for levels 0..5 (16B entry = corners (x..x+1)x(y..y+1)) ----
__device__ __host__ constexpr int DRES(int l) {
    constexpr int r[6] = {16, 22, 30, 42, 58, 80};
    return r[l];
}
// quad entries per level: (r-1)*(r-1)*r ; offsets cumulative
__device__ __host__ constexpr uint32_t QOFF(int l) {
    constexpr uint32_t o[7] = {0, 3600, 13302, 38532, 109134, 297576, 796856};
    return o[l];
}
#define QUAD_ENTRIES 796856u
#define HASH16_ENTRIES (10u << 19)                  // levels 6..15, u32 (f16x2) each
#define HASH16_BYTES ((size_t)HASH16_ENTRIES * 4)
#define QUAD_BYTES   ((size_t)QUAD_ENTRIES * 16)
#define PREP_TOTAL   (HASH16_ENTRIES + QUAD_ENTRIES)

// ---------------- one-time table prep: f16 convert + quad builds, ONE dispatch ----------------

__device__ __forceinline__ uint32_t fetch_pack(const float* __restrict__ emb,
                                               int l, uint32_t x, uint32_t y, uint32_t z)
{
    const uint32_t h = (x ^ (y * P1) ^ (z * P2)) & HMASK;
    const float2 v = *reinterpret_cast<const float2*>(emb + (((size_t)l << 19) + h) * 2);
    __half2 hv = __floats2half2_rn(v.x, v.y);
    return *reinterpret_cast<uint32_t*>(&hv);
}

template <int L>
__device__ __forceinline__ void qbuild(uint32_t rel, const float* __restrict__ emb,
                                       uint4* __restrict__ quad)
{
    constexpr int r = DRES(L);
    constexpr int rW = r - 1;
    const uint32_t fz = rel / (uint32_t)(rW * rW);
    const uint32_t rem = rel - fz * (uint32_t)(rW * rW);
    const uint32_t fy = rem / (uint32_t)rW;
    const uint32_t fx = rem - fy * (uint32_t)rW;
    uint4 q;
    q.x = fetch_pack(emb, L, fx,     fy,     fz);
    q.y = fetch_pack(emb, L, fx + 1, fy,     fz);
    q.z = fetch_pack(emb, L, fx,     fy + 1, fz);
    q.w = fetch_pack(emb, L, fx + 1, fy + 1, fz);
    quad[QOFF(L) + rel] = q;
}

__global__ __launch_bounds__(BLOCK) void prep_kernel(
    const float* __restrict__ emb,
    uint32_t* __restrict__ tab16,
    uint4* __restrict__ quad)
{
    const uint32_t i = blockIdx.x * BLOCK + threadIdx.x;
    if (i < HASH16_ENTRIES) {
        const float2 v = *reinterpret_cast<const float2*>(
            emb + (((size_t)(6u << 19)) + i) * 2);
        __half2 hv = __floats2half2_rn(v.x, v.y);
        __builtin_nontemporal_store(*reinterpret_cast<uint32_t*>(&hv), &tab16[i]);
    } else if (i < PREP_TOTAL) {
        const uint32_t j = i - HASH16_ENTRIES;
        if      (j < QOFF(1)) qbuild<0>(j - QOFF(0), emb, quad);
        else if (j < QOFF(2)) qbuild<1>(j - QOFF(1), emb, quad);
        else if (j < QOFF(3)) qbuild<2>(j - QOFF(2), emb, quad);
        else if (j < QOFF(4)) qbuild<3>(j - QOFF(3), emb, quad);
        else if (j < QOFF(5)) qbuild<4>(j - QOFF(4), emb, quad);
        else                  qbuild<5>(j - QOFF(5), emb, quad);
    }
}

// ---------------- shared helpers ----------------

struct PointCtx { float nx, ny, nz; bool valid; };

__device__ __forceinline__ PointCtx make_ctx(const float* __restrict__ xyz, int pt, int B,
                                             float mn0, float mn1, float mn2,
                                             float inv0, float inv1, float inv2)
{
    PointCtx P;
    P.nx = P.ny = P.nz = 0.0f;
    P.valid = false;
    if (pt < B) {
        const float x = xyz[3 * pt + 0];
        const float y = xyz[3 * pt + 1];
        const float z = xyz[3 * pt + 2];
        P.nx = (x - mn0) * inv0;
        P.ny = (y - mn1) * inv1;
        P.nz = (z - mn2) * inv2;
        P.valid = (P.nx >= 0.0f) && (P.nx <= 1.0f) &&
                  (P.ny >= 0.0f) && (P.ny <= 1.0f) &&
                  (P.nz >= 0.0f) && (P.nz <= 1.0f);
    }
    return P;
}

__device__ __forceinline__ void frac_setup(const PointCtx& P, int r,
                                           int& fx, int& fy, int& fz,
                                           float& wx0, float& wx1,
                                           float& wy0, float& wy1,
                                           float& wz0, float& wz1)
{
    const float rm1 = (float)(r - 1);
    const float px = P.nx * rm1, py = P.ny * rm1, pz = P.nz * rm1;
    fx = (int)floorf(px); fx = min(max(fx, 0), r - 2);
    fy = (int)floorf(py); fy = min(max(fy, 0), r - 2);
    fz = (int)floorf(pz); fz = min(max(fz, 0), r - 2);
    wx1 = px - (float)fx; wx0 = 1.0f - wx1;
    wy1 = py - (float)fy; wy0 = 1.0f - wy1;
    wz1 = pz - (float)fz; wz0 = 1.0f - wz1;
}

__device__ __forceinline__ float2 h2f(uint32_t e)
{
    return __half22float2(*reinterpret_cast<const __half2*>(&e));
}

// dense quad path: 2 x dwordx4 loads (planes fz, fz+1)
__device__ __forceinline__ float2 quad_encode(const PointCtx& P, int r, uint32_t qoff,
                                              const uint4* __restrict__ quad)
{
    int fx, fy, fz; float wx0, wx1, wy0, wy1, wz0, wz1;
    frac_setup(P, r, fx, fy, fz, wx0, wx1, wy0, wy1, wz0, wz1);
    const int rW = r - 1;
    const uint32_t base = qoff + (uint32_t)(fx + fy * rW + fz * rW * rW);
    const uint4 q0 = quad[base];
    const uint4 q1 = quad[base + (uint32_t)(rW * rW)];

    const float2 a0 = h2f(q0.x), b0 = h2f(q0.y), c0 = h2f(q0.z), d0 = h2f(q0.w);
    const float2 a1 = h2f(q1.x), b1 = h2f(q1.y), c1 = h2f(q1.z), d1 = h2f(q1.w);

    const float p0x = wy0 * (wx0 * a0.x + wx1 * b0.x) + wy1 * (wx0 * c0.x + wx1 * d0.x);
    const float p0y = wy0 * (wx0 * a0.y + wx1 * b0.y) + wy1 * (wx0 * c0.y + wx1 * d0.y);
    const float p1x = wy0 * (wx0 * a1.x + wx1 * b1.x) + wy1 * (wx0 * c1.x + wx1 * d1.x);
    const float p1y = wy0 * (wx0 * a1.y + wx1 * b1.y) + wy1 * (wx0 * c1.y + wx1 * d1.y);

    float2 o;
    o.x = P.valid ? (wz0 * p0x + wz1 * p1x) : 0.0f;
    o.y = P.valid ? (wz0 * p0y + wz1 * p1y) : 0.0f;
    return o;
}

// hash path: 4 aligned 8B pair loads + one exec-masked region of 4 singles (odd fx)
__device__ __forceinline__ float2 hash_encode(const PointCtx& P, int r,
                                              const uint32_t* __restrict__ lt)
{
    int fx, fy, fz; float wx0, wx1, wy0, wy1, wz0, wz1;
    frac_setup(P, r, fx, fy, fz, wx0, wx1, wy0, wy1, wz0, wz1);
    const uint32_t hx0 = (uint32_t)fx;
    const uint32_t hy0 = (uint32_t)fy * P1, hy1 = hy0 + P1;
    const uint32_t hz0 = (uint32_t)fz * P2, hz1 = hz0 + P2;
    const bool oddx = (fx & 1) != 0;

    uint32_t i0[4];
    uint2 pr[4];
    #pragma unroll
    for (int yz = 0; yz < 4; ++yz) {
        const uint32_t rest = ((yz & 1) ? hy1 : hy0) ^ ((yz & 2) ? hz1 : hz0);
        i0[yz] = (hx0 ^ rest) & HMASK;
        pr[yz] = *reinterpret_cast<const uint2*>(lt + (i0[yz] & ~1u));
    }
    uint32_t e1x[4] = {0, 0, 0, 0};
    if (oddx) {            // single divergent region; masked lanes issue no requests
        #pragma unroll
        for (int yz = 0; yz < 4; ++yz) {
            const uint32_t rest = ((yz & 1) ? hy1 : hy0) ^ ((yz & 2) ? hz1 : hz0);
            e1x[yz] = lt[((hx0 + 1u) ^ rest) & HMASK];
        }
    }

    float acc0 = 0.0f, acc1 = 0.0f;
    #pragma unroll
    for (int yz = 0; yz < 4; ++yz) {
        const float wyz = ((yz & 1) ? wy1 : wy0) * ((yz & 2) ? wz1 : wz0);
        const uint32_t eA = (i0[yz] & 1u) ? pr[yz].y : pr[yz].x;   // corner fx
        const uint32_t eB0 = (i0[yz] & 1u) ? pr[yz].x : pr[yz].y;  // corner fx+1 if even
        const uint32_t eB = oddx ? e1x[yz] : eB0;
        const float2 cA = h2f(eA);
        const float2 cB = h2f(eB);
        acc0 += wyz * (wx0 * cA.x + wx1 * cB.x);
        acc1 += wyz * (wx0 * cA.y + wx1 * cB.y);
    }
    float2 o;
    o.x = P.valid ? acc0 : 0.0f;
    o.y = P.valid ? acc1 : 0.0f;
    return o;
}

__device__ __forceinline__ void nt_store_f2h(uint32_t* p, float2 v)
{
    __half2 h = __floats2half2_rn(v.x, v.y);
    __builtin_nontemporal_store(*reinterpret_cast<uint32_t*>(&h), p);
}

// ---------------- mega gather: 12 level-major segments in ONE dispatch ----------------
// seg 0     : dense (quad) levels 0-4
// seg 1     : dense (quad) level 5
// seg 2..11 : hash levels 6..15
__global__ __launch_bounds__(BLOCK, 4) void gather_mega_kernel(
    const float* __restrict__ xyz,
    const uint32_t* __restrict__ tab16,
    const uint4* __restrict__ quad,
    const float* __restrict__ minv,
    const float* __restrict__ maxv,
    uint32_t* __restrict__ slab,
    int B, int blocks2)
{
    constexpr int HRES[10] = {111, 154, 212, 294, 406, 561, 776, 1072, 1482, 2048};

    const int seg = blockIdx.x / blocks2;
    const int blk = blockIdx.x - seg * blocks2;

    const int t = threadIdx.x;
    const int p0 = blk * (NPT * BLOCK) + t;
    const int p1 = p0 + BLOCK;

    const float mn0 = minv[0], mn1 = minv[1], mn2 = minv[2];
    const float inv0 = 1.0f / (maxv[0] - mn0);
    const float inv1 = 1.0f / (maxv[1] - mn1);
    const float inv2 = 1.0f / (maxv[2] - mn2);

    const PointCtx A  = make_ctx(xyz, p0, B, mn0, mn1, mn2, inv0, inv1, inv2);
    const PointCtx Bc = make_ctx(xyz, p1, B, mn0, mn1, mn2, inv0, inv1, inv2);

    if (seg == 0) {
        #pragma unroll
        for (int l = 0; l < 5; ++l) {
            const float2 o0 = quad_encode(A,  DRES(l), QOFF(l), quad);
            const float2 o1 = quad_encode(Bc, DRES(l), QOFF(l), quad);
            if (p0 < B) nt_store_f2h(&slab[(size_t)l * B + p0], o0);
            if (p1 < B) nt_store_f2h(&slab[(size_t)l * B + p1], o1);
        }
    } else if (seg == 1) {
        const float2 o0 = quad_encode(A,  DRES(5), QOFF(5), quad);
        const float2 o1 = quad_encode(Bc, DRES(5), QOFF(5), quad);
        if (p0 < B) nt_store_f2h(&slab[(size_t)5 * B + p0], o0);
        if (p1 < B) nt_store_f2h(&slab[(size_t)5 * B + p1], o1);
    } else {
        const int l = seg + 4;                    // 6..15
        const int r = HRES[seg - 2];
        const uint32_t* __restrict__ lt = tab16 + ((size_t)(l - 6) << 19);
        const float2 o0 = hash_encode(A,  r, lt);
        const float2 o1 = hash_encode(Bc, r, lt);
        if (p0 < B) nt_store_f2h(&slab[(size_t)l * B + p0], o0);
        if (p1 < B) nt_store_f2h(&slab[(size_t)l * B + p1], o1);
    }
}

// ---------------- final transpose: slab[16][B] (f16x2) -> out[B][32] (f32) ----------------
__global__ __launch_bounds__(BLOCK) void transpose_kernel(
    const uint32_t* __restrict__ slab,
    float* __restrict__ out,
    int B)
{
    __shared__ float s[32][BLOCK + 1];
    const int t = threadIdx.x;
    const int pt = blockIdx.x * BLOCK + t;

    #pragma unroll
    for (int l = 0; l < NLEVELS; ++l) {
        float2 v = make_float2(0.0f, 0.0f);
        if (pt < B) {
            const uint32_t bits = __builtin_nontemporal_load(&slab[(size_t)l * B + pt]);
            v = h2f(bits);
        }
        s[2 * l + 0][t] = v.x;
        s[2 * l + 1][t] = v.y;
    }
    __syncthreads();

    const size_t chunk = (size_t)blockIdx.x * (BLOCK * 32);
    const size_t total = (size_t)B * 32;
    #pragma unroll
    for (int k = 0; k < 32; ++k) {
        const int flat = k * BLOCK + t;
        const int p = flat >> 5;
        const int c = flat & 31;
        const size_t g = chunk + (size_t)flat;
        if (g < total) __builtin_nontemporal_store(s[c][p], &out[g]);
    }
}

// ---------------- fallback: single fused f32 kernel ----------------
__global__ __launch_bounds__(BLOCK) void hashgrid_fused_kernel(
    const float* __restrict__ xyz,
    const float* __restrict__ emb,
    const float* __restrict__ minv,
    const float* __restrict__ maxv,
    float* __restrict__ out,
    int B)
{
    constexpr int RES[NLEVELS] = {16, 22, 30, 42, 58, 80, 111, 154,
                                  212, 294, 406, 561, 776, 1072, 1482, 2048};
    __shared__ float s[32][BLOCK + 1];
    const int t = threadIdx.x;
    const int pt = blockIdx.x * BLOCK + t;

    const float mn0 = minv[0], mn1 = minv[1], mn2 = minv[2];
    const float inv0 = 1.0f / (maxv[0] - mn0);
    const float inv1 = 1.0f / (maxv[1] - mn1);
    const float inv2 = 1.0f / (maxv[2] - mn2);

    const PointCtx P = make_ctx(xyz, pt, B, mn0, mn1, mn2, inv0, inv1, inv2);

    #pragma unroll
    for (int l = 0; l < NLEVELS; ++l) {
        int fx, fy, fz; float wx0, wx1, wy0, wy1, wz0, wz1;
        frac_setup(P, RES[l], fx, fy, fz, wx0, wx1, wy0, wy1, wz0, wz1);
        const uint32_t hx0 = (uint32_t)fx, hx1 = hx0 + 1u;
        const uint32_t hy0 = (uint32_t)fy * P1, hy1 = hy0 + P1;
        const uint32_t hz0 = (uint32_t)fz * P2, hz1 = hz0 + P2;
        const float* __restrict__ lemb = emb + ((size_t)l << 20);
        float acc0 = 0.0f, acc1 = 0.0f;
        #pragma unroll
        for (int k = 0; k < 8; ++k) {
            const uint32_t h = (((k & 1) ? hx1 : hx0) ^
                                ((k & 2) ? hy1 : hy0) ^
                                ((k & 4) ? hz1 : hz0)) & HMASK;
            const float2 f = *reinterpret_cast<const float2*>(lemb + ((size_t)h << 1));
            const float w = ((k & 1) ? wx1 : wx0) * ((k & 2) ? wy1 : wy0) * ((k & 4) ? wz1 : wz0);
            acc0 = fmaf(w, f.x, acc0);
            acc1 = fmaf(w, f.y, acc1);
        }
        s[2 * l + 0][t] = P.valid ? acc0 : 0.0f;
        s[2 * l + 1][t] = P.valid ? acc1 : 0.0f;
    }
    __syncthreads();
    const size_t chunk = (size_t)blockIdx.x * (BLOCK * 32);
    const size_t total = (size_t)B * 32;
    #pragma unroll
    for (int k = 0; k < 32; ++k) {
        const int flat = k * BLOCK + t;
        const int p = flat >> 5;
        const int c = flat & 31;
        const size_t g = chunk + (size_t)flat;
        if (g < total) out[g] = s[c][p];
    }
}

extern "C" void kernel_launch(void* const* d_in, const int* in_sizes, int n_in,
                              void* d_out, int out_size, void* d_ws, size_t ws_size,
                              hipStream_t stream) {
    const float* xyz = (const float*)d_in[0];
    const float* emb = (const float*)d_in[1];
    const float* mn  = (const float*)d_in[2];
    const float* mx  = (const float*)d_in[3];
    float* out = (float*)d_out;

    const int B = in_sizes[0] / 3;
    const int blocks1 = (B + BLOCK - 1) / BLOCK;
    const int blocks2 = (B + NPT * BLOCK - 1) / (NPT * BLOCK);

    const size_t slab_bytes = (size_t)NLEVELS * (size_t)B * 4;   // multiple of 16 for B=1M
    const size_t ws_needed = slab_bytes + HASH16_BYTES + QUAD_BYTES;

    if (ws_size >= ws_needed) {
        uint32_t* slab  = (uint32_t*)d_ws;
        uint32_t* tab16 = (uint32_t*)((char*)d_ws + slab_bytes);
        uint4*    quad  = (uint4*)((char*)d_ws + slab_bytes + HASH16_BYTES);

        hipLaunchKernelGGL(prep_kernel,
                           dim3((PREP_TOTAL + BLOCK - 1) / BLOCK), dim3(BLOCK),
                           0, stream, emb, tab16, quad);

        hipLaunchKernelGGL(gather_mega_kernel, dim3(12 * blocks2), dim3(BLOCK), 0, stream,
                           xyz, tab16, quad, mn, mx, slab, B, blocks2);

        hipLaunchKernelGGL(transpose_kernel, dim3(blocks1), dim3(BLOCK), 0, stream,
                           slab, out, B);
    } else {
        hipLaunchKernelGGL(hashgrid_fused_kernel, dim3(blocks1), dim3(BLOCK), 0, stream,
                           xyz, emb, mn, mx, out, B);
    }
}

// Round 10
// 330.456 us; speedup vs baseline: 1.1152x; 1.1152x over previous
//
#include <hip/hip_runtime.h>
#include <hip/hip_fp16.h>
#include <stdint.h>

#define NLEVELS 16
#define BLOCK 256
#define NPT 2

#define P1 2654435761u
#define P2 805459861u
#define HMASK 0x7FFFFu

// ---- dense x-pair tables for levels 0..5 ----
// entry dup[off + x + y*r + z*r*r] = (e(x,y,z), e(x+1,y,z)) as 2 x f16x2 (8B aligned)
__device__ __host__ constexpr int DRES(int l) {
    constexpr int r[6] = {16, 22, 30, 42, 58, 80};
    return r[l];
}
__device__ __host__ constexpr uint32_t DOFF(int l) {
    constexpr uint32_t o[7] = {0, 4096, 14744, 41744, 115832, 310944, 822944};
    return o[l];
}
#define DENSE_ENTRIES 822944u                       // sum of r^3, l=0..5
#define HASH16_ENTRIES (10u << 19)                  // levels 6..15, u32 (f16x2) each
#define HASH16_BYTES ((size_t)HASH16_ENTRIES * 4)
#define DUP_BYTES    ((size_t)DENSE_ENTRIES * 8)
#define PREP_TOTAL   (HASH16_ENTRIES + DENSE_ENTRIES)

// ---------------- one-time table prep: f16 convert + dup builds, ONE dispatch ----------------

__device__ __forceinline__ uint32_t fetch_pack(const float* __restrict__ emb,
                                               int l, uint32_t x, uint32_t y, uint32_t z)
{
    const uint32_t h = (x ^ (y * P1) ^ (z * P2)) & HMASK;
    const float2 v = *reinterpret_cast<const float2*>(emb + (((size_t)l << 19) + h) * 2);
    __half2 hv = __floats2half2_rn(v.x, v.y);
    return *reinterpret_cast<uint32_t*>(&hv);
}

__global__ __launch_bounds__(BLOCK) void prep_kernel(
    const float* __restrict__ emb,
    uint32_t* __restrict__ tab16,
    uint2* __restrict__ dup)
{
    const uint32_t i = blockIdx.x * BLOCK + threadIdx.x;
    if (i < HASH16_ENTRIES) {
        const float2 v = *reinterpret_cast<const float2*>(
            emb + (((size_t)(6u << 19)) + i) * 2);
        __half2 hv = __floats2half2_rn(v.x, v.y);
        __builtin_nontemporal_store(*reinterpret_cast<uint32_t*>(&hv), &tab16[i]);
    } else if (i < PREP_TOTAL) {
        const uint32_t j = i - HASH16_ENTRIES;
        int l = 0;
        #pragma unroll
        for (int q = 1; q < 6; ++q) if (j >= DOFF(q)) l = q;
        const int r = DRES(l);
        const uint32_t rel = j - DOFF(l);
        const uint32_t z = rel / (uint32_t)(r * r);
        const uint32_t rem = rel - z * (uint32_t)(r * r);
        const uint32_t y = rem / (uint32_t)r;
        const uint32_t x = rem - y * (uint32_t)r;
        const uint32_t x1 = min(x + 1u, (uint32_t)(r - 1));
        uint2 e;
        e.x = fetch_pack(emb, l, x,  y, z);
        e.y = fetch_pack(emb, l, x1, y, z);
        dup[j] = e;
    }
}

// ---------------- shared helpers ----------------

struct PointCtx { float nx, ny, nz; bool valid; };

__device__ __forceinline__ PointCtx make_ctx(const float* __restrict__ xyz, int pt, int B,
                                             float mn0, float mn1, float mn2,
                                             float inv0, float inv1, float inv2)
{
    PointCtx P;
    P.nx = P.ny = P.nz = 0.0f;
    P.valid = false;
    if (pt < B) {
        const float x = xyz[3 * pt + 0];
        const float y = xyz[3 * pt + 1];
        const float z = xyz[3 * pt + 2];
        P.nx = (x - mn0) * inv0;
        P.ny = (y - mn1) * inv1;
        P.nz = (z - mn2) * inv2;
        P.valid = (P.nx >= 0.0f) && (P.nx <= 1.0f) &&
                  (P.ny >= 0.0f) && (P.ny <= 1.0f) &&
                  (P.nz >= 0.0f) && (P.nz <= 1.0f);
    }
    return P;
}

__device__ __forceinline__ void frac_setup(const PointCtx& P, int r,
                                           int& fx, int& fy, int& fz,
                                           float& wx0, float& wx1,
                                           float& wy0, float& wy1,
                                           float& wz0, float& wz1)
{
    const float rm1 = (float)(r - 1);
    const float px = P.nx * rm1, py = P.ny * rm1, pz = P.nz * rm1;
    fx = (int)floorf(px); fx = min(max(fx, 0), r - 2);
    fy = (int)floorf(py); fy = min(max(fy, 0), r - 2);
    fz = (int)floorf(pz); fz = min(max(fz, 0), r - 2);
    wx1 = px - (float)fx; wx0 = 1.0f - wx1;
    wy1 = py - (float)fy; wy0 = 1.0f - wy1;
    wz1 = pz - (float)fz; wz0 = 1.0f - wz1;
}

__device__ __forceinline__ float2 h2f(uint32_t e)
{
    return __half22float2(*reinterpret_cast<const __half2*>(&e));
}

// dense path: 4 aligned 8B loads, each covering the (x, x+1) corner pair
__device__ __forceinline__ float2 dup_encode(const PointCtx& P, int r, uint32_t off,
                                             const uint2* __restrict__ dup)
{
    int fx, fy, fz; float wx0, wx1, wy0, wy1, wz0, wz1;
    frac_setup(P, r, fx, fy, fz, wx0, wx1, wy0, wy1, wz0, wz1);
    const uint32_t base = off + (uint32_t)(fx + fy * r + fz * r * r);

    const uint2 q00 = dup[base];                               // (y0, z0)
    const uint2 q10 = dup[base + (uint32_t)r];                 // (y1, z0)
    const uint2 q01 = dup[base + (uint32_t)(r * r)];           // (y0, z1)
    const uint2 q11 = dup[base + (uint32_t)(r + r * r)];       // (y1, z1)

    float acc0 = 0.0f, acc1 = 0.0f;
    {
        const float w = wy0 * wz0;
        const float2 a = h2f(q00.x), b = h2f(q00.y);
        acc0 += w * (wx0 * a.x + wx1 * b.x);
        acc1 += w * (wx0 * a.y + wx1 * b.y);
    }
    {
        const float w = wy1 * wz0;
        const float2 a = h2f(q10.x), b = h2f(q10.y);
        acc0 += w * (wx0 * a.x + wx1 * b.x);
        acc1 += w * (wx0 * a.y + wx1 * b.y);
    }
    {
        const float w = wy0 * wz1;
        const float2 a = h2f(q01.x), b = h2f(q01.y);
        acc0 += w * (wx0 * a.x + wx1 * b.x);
        acc1 += w * (wx0 * a.y + wx1 * b.y);
    }
    {
        const float w = wy1 * wz1;
        const float2 a = h2f(q11.x), b = h2f(q11.y);
        acc0 += w * (wx0 * a.x + wx1 * b.x);
        acc1 += w * (wx0 * a.y + wx1 * b.y);
    }
    float2 o;
    o.x = P.valid ? acc0 : 0.0f;
    o.y = P.valid ? acc1 : 0.0f;
    return o;
}

// hash path (R7-identical): 8 independent u32 loads, branchless
__device__ __forceinline__ float2 hash_encode(const PointCtx& P, int r,
                                              const uint32_t* __restrict__ lt)
{
    int fx, fy, fz; float wx0, wx1, wy0, wy1, wz0, wz1;
    frac_setup(P, r, fx, fy, fz, wx0, wx1, wy0, wy1, wz0, wz1);
    const uint32_t hx0 = (uint32_t)fx,      hx1 = hx0 + 1u;
    const uint32_t hy0 = (uint32_t)fy * P1, hy1 = hy0 + P1;
    const uint32_t hz0 = (uint32_t)fz * P2, hz1 = hz0 + P2;

    uint32_t e[8];
    #pragma unroll
    for (int k = 0; k < 8; ++k) {
        const uint32_t h = (((k & 1) ? hx1 : hx0) ^
                            ((k & 2) ? hy1 : hy0) ^
                            ((k & 4) ? hz1 : hz0)) & HMASK;
        e[k] = lt[h];
    }
    float acc0 = 0.0f, acc1 = 0.0f;
    #pragma unroll
    for (int k = 0; k < 8; ++k) {
        const float w = ((k & 1) ? wx1 : wx0) * ((k & 2) ? wy1 : wy0) * ((k & 4) ? wz1 : wz0);
        const float2 f = h2f(e[k]);
        acc0 = fmaf(w, f.x, acc0);
        acc1 = fmaf(w, f.y, acc1);
    }
    float2 o;
    o.x = P.valid ? acc0 : 0.0f;
    o.y = P.valid ? acc1 : 0.0f;
    return o;
}

__device__ __forceinline__ void nt_store_f2h(uint32_t* p, float2 v)
{
    __half2 h = __floats2half2_rn(v.x, v.y);
    __builtin_nontemporal_store(*reinterpret_cast<uint32_t*>(&h), p);
}

// ---------------- mega gather: 12 level-major segments in ONE dispatch ----------------
// seg 0     : dense (dup) levels 0-4
// seg 1     : dense (dup) level 5
// seg 2..11 : hash levels 6..15
__global__ __launch_bounds__(BLOCK, 4) void gather_mega_kernel(
    const float* __restrict__ xyz,
    const uint32_t* __restrict__ tab16,
    const uint2* __restrict__ dup,
    const float* __restrict__ minv,
    const float* __restrict__ maxv,
    uint32_t* __restrict__ slab,
    int B, int blocks2)
{
    constexpr int HRES[10] = {111, 154, 212, 294, 406, 561, 776, 1072, 1482, 2048};

    const int seg = blockIdx.x / blocks2;
    const int blk = blockIdx.x - seg * blocks2;

    const int t = threadIdx.x;
    const int p0 = blk * (NPT * BLOCK) + t;
    const int p1 = p0 + BLOCK;

    const float mn0 = minv[0], mn1 = minv[1], mn2 = minv[2];
    const float inv0 = 1.0f / (maxv[0] - mn0);
    const float inv1 = 1.0f / (maxv[1] - mn1);
    const float inv2 = 1.0f / (maxv[2] - mn2);

    const PointCtx A  = make_ctx(xyz, p0, B, mn0, mn1, mn2, inv0, inv1, inv2);
    const PointCtx Bc = make_ctx(xyz, p1, B, mn0, mn1, mn2, inv0, inv1, inv2);

    if (seg == 0) {
        #pragma unroll
        for (int l = 0; l < 5; ++l) {
            const float2 o0 = dup_encode(A,  DRES(l), DOFF(l), dup);
            const float2 o1 = dup_encode(Bc, DRES(l), DOFF(l), dup);
            if (p0 < B) nt_store_f2h(&slab[(size_t)l * B + p0], o0);
            if (p1 < B) nt_store_f2h(&slab[(size_t)l * B + p1], o1);
        }
    } else if (seg == 1) {
        const float2 o0 = dup_encode(A,  DRES(5), DOFF(5), dup);
        const float2 o1 = dup_encode(Bc, DRES(5), DOFF(5), dup);
        if (p0 < B) nt_store_f2h(&slab[(size_t)5 * B + p0], o0);
        if (p1 < B) nt_store_f2h(&slab[(size_t)5 * B + p1], o1);
    } else {
        const int l = seg + 4;                    // 6..15
        const int r = HRES[seg - 2];
        const uint32_t* __restrict__ lt = tab16 + ((size_t)(l - 6) << 19);
        const float2 o0 = hash_encode(A,  r, lt);
        const float2 o1 = hash_encode(Bc, r, lt);
        if (p0 < B) nt_store_f2h(&slab[(size_t)l * B + p0], o0);
        if (p1 < B) nt_store_f2h(&slab[(size_t)l * B + p1], o1);
    }
}

// ---------------- final transpose: slab[16][B] (f16x2) -> out[B][32] (f32) ----------------
__global__ __launch_bounds__(BLOCK) void transpose_kernel(
    const uint32_t* __restrict__ slab,
    float* __restrict__ out,
    int B)
{
    __shared__ float s[32][BLOCK + 1];
    const int t = threadIdx.x;
    const int pt = blockIdx.x * BLOCK + t;

    #pragma unroll
    for (int l = 0; l < NLEVELS; ++l) {
        float2 v = make_float2(0.0f, 0.0f);
        if (pt < B) {
            const uint32_t bits = __builtin_nontemporal_load(&slab[(size_t)l * B + pt]);
            v = h2f(bits);
        }
        s[2 * l + 0][t] = v.x;
        s[2 * l + 1][t] = v.y;
    }
    __syncthreads();

    const size_t chunk = (size_t)blockIdx.x * (BLOCK * 32);
    const size_t total = (size_t)B * 32;
    #pragma unroll
    for (int k = 0; k < 32; ++k) {
        const int flat = k * BLOCK + t;
        const int p = flat >> 5;
        const int c = flat & 31;
        const size_t g = chunk + (size_t)flat;
        if (g < total) __builtin_nontemporal_store(s[c][p], &out[g]);
    }
}

// ---------------- fallback: single fused f32 kernel ----------------
__global__ __launch_bounds__(BLOCK) void hashgrid_fused_kernel(
    const float* __restrict__ xyz,
    const float* __restrict__ emb,
    const float* __restrict__ minv,
    const float* __restrict__ maxv,
    float* __restrict__ out,
    int B)
{
    constexpr int RES[NLEVELS] = {16, 22, 30, 42, 58, 80, 111, 154,
                                  212, 294, 406, 561, 776, 1072, 1482, 2048};
    __shared__ float s[32][BLOCK + 1];
    const int t = threadIdx.x;
    const int pt = blockIdx.x * BLOCK + t;

    const float mn0 = minv[0], mn1 = minv[1], mn2 = minv[2];
    const float inv0 = 1.0f / (maxv[0] - mn0);
    const float inv1 = 1.0f / (maxv[1] - mn1);
    const float inv2 = 1.0f / (maxv[2] - mn2);

    const PointCtx P = make_ctx(xyz, pt, B, mn0, mn1, mn2, inv0, inv1, inv2);

    #pragma unroll
    for (int l = 0; l < NLEVELS; ++l) {
        int fx, fy, fz; float wx0, wx1, wy0, wy1, wz0, wz1;
        frac_setup(P, RES[l], fx, fy, fz, wx0, wx1, wy0, wy1, wz0, wz1);
        const uint32_t hx0 = (uint32_t)fx, hx1 = hx0 + 1u;
        const uint32_t hy0 = (uint32_t)fy * P1, hy1 = hy0 + P1;
        const uint32_t hz0 = (uint32_t)fz * P2, hz1 = hz0 + P2;
        const float* __restrict__ lemb = emb + ((size_t)l << 20);
        float acc0 = 0.0f, acc1 = 0.0f;
        #pragma unroll
        for (int k = 0; k < 8; ++k) {
            const uint32_t h = (((k & 1) ? hx1 : hx0) ^
                                ((k & 2) ? hy1 : hy0) ^
                                ((k & 4) ? hz1 : hz0)) & HMASK;
            const float2 f = *reinterpret_cast<const float2*>(lemb + ((size_t)h << 1));
            const float w = ((k & 1) ? wx1 : wx0) * ((k & 2) ? wy1 : wy0) * ((k & 4) ? wz1 : wz0);
            acc0 = fmaf(w, f.x, acc0);
            acc1 = fmaf(w, f.y, acc1);
        }
        s[2 * l + 0][t] = P.valid ? acc0 : 0.0f;
        s[2 * l + 1][t] = P.valid ? acc1 : 0.0f;
    }
    __syncthreads();
    const size_t chunk = (size_t)blockIdx.x * (BLOCK * 32);
    const size_t total = (size_t)B * 32;
    #pragma unroll
    for (int k = 0; k < 32; ++k) {
        const int flat = k * BLOCK + t;
        const int p = flat >> 5;
        const int c = flat & 31;
        const size_t g = chunk + (size_t)flat;
        if (g < total) out[g] = s[c][p];
    }
}

extern "C" void kernel_launch(void* const* d_in, const int* in_sizes, int n_in,
                              void* d_out, int out_size, void* d_ws, size_t ws_size,
                              hipStream_t stream) {
    const float* xyz = (const float*)d_in[0];
    const float* emb = (const float*)d_in[1];
    const float* mn  = (const float*)d_in[2];
    const float* mx  = (const float*)d_in[3];
    float* out = (float*)d_out;

    const int B = in_sizes[0] / 3;
    const int blocks1 = (B + BLOCK - 1) / BLOCK;
    const int blocks2 = (B + NPT * BLOCK - 1) / (NPT * BLOCK);

    const size_t slab_bytes = (size_t)NLEVELS * (size_t)B * 4;   // 64 MB at B=1M
    const size_t ws_needed = slab_bytes + HASH16_BYTES + DUP_BYTES;

    if (ws_size >= ws_needed) {
        uint32_t* slab  = (uint32_t*)d_ws;
        uint32_t* tab16 = (uint32_t*)((char*)d_ws + slab_bytes);
        uint2*    dup   = (uint2*)((char*)d_ws + slab_bytes + HASH16_BYTES);

        hipLaunchKernelGGL(prep_kernel,
                           dim3((PREP_TOTAL + BLOCK - 1) / BLOCK), dim3(BLOCK),
                           0, stream, emb, tab16, dup);

        hipLaunchKernelGGL(gather_mega_kernel, dim3(12 * blocks2), dim3(BLOCK), 0, stream,
                           xyz, tab16, dup, mn, mx, slab, B, blocks2);

        hipLaunchKernelGGL(transpose_kernel, dim3(blocks1), dim3(BLOCK), 0, stream,
                           slab, out, B);
    } else {
        hipLaunchKernelGGL(hashgrid_fused_kernel, dim3(blocks1), dim3(BLOCK), 0, stream,
                           xyz, emb, mn, mx, out, B);
    }
}

// Round 11
// 313.040 us; speedup vs baseline: 1.1772x; 1.0556x over previous
//
#include <hip/hip_runtime.h>
#include <hip/hip_fp16.h>
#include <stdint.h>

#define NLEVELS 16
#define BLOCK 256
#define NPT 2

#define P1 2654435761u
#define P2 805459861u
#define HMASK 0x7FFFFu

// dense tables for levels 0..5 (r^3 <= 2^19): entry = f16x2 packed in u32
__device__ __host__ constexpr int DRES(int l) {
    constexpr int r[6] = {16, 22, 30, 42, 58, 80};
    return r[l];
}
__device__ __host__ constexpr uint32_t DOFF(int l) {
    constexpr uint32_t o[7] = {0, 4096, 14744, 41744, 115832, 310944, 822944};
    return o[l];
}
#define DENSE_ENTRIES 822944u                       // sum of r^3, l=0..5
#define HASH16_ENTRIES (10u << 19)                  // levels 6..15
#define HASH16_BYTES ((size_t)HASH16_ENTRIES * 4)
#define DENSE_BYTES  ((size_t)DENSE_ENTRIES * 4)
#define PREP_TOTAL   (HASH16_ENTRIES + DENSE_ENTRIES)

// ---------------- one-time table prep: convert + dense builds, ONE dispatch ----------------
__global__ __launch_bounds__(BLOCK) void prep_kernel(
    const float* __restrict__ emb,
    uint32_t* __restrict__ tab16,
    uint32_t* __restrict__ dense)
{
    const uint32_t i = blockIdx.x * BLOCK + threadIdx.x;
    if (i < HASH16_ENTRIES) {
        // f32 hash table levels 6..15 -> f16x2
        const float2 v = *reinterpret_cast<const float2*>(
            emb + (((size_t)(6u << 19)) + i) * 2);
        __half2 hv = __floats2half2_rn(v.x, v.y);
        __builtin_nontemporal_store(*reinterpret_cast<uint32_t*>(&hv), &tab16[i]);
    } else if (i < PREP_TOTAL) {
        // dense re-index for levels 0..5: dense[x + y*r + z*r^2] = emb[hash(x,y,z)]
        const uint32_t j = i - HASH16_ENTRIES;
        int l = 0;
        #pragma unroll
        for (int q = 1; q < 6; ++q) if (j >= DOFF(q)) l = q;
        const int r = DRES(l);
        const uint32_t rel = j - DOFF(l);
        const int z = rel / (uint32_t)(r * r);
        const uint32_t rem = rel - (uint32_t)z * (uint32_t)(r * r);
        const int y = rem / (uint32_t)r;
        const int x = rem - (uint32_t)y * (uint32_t)r;
        const uint32_t h = ((uint32_t)x ^ ((uint32_t)y * P1) ^ ((uint32_t)z * P2)) & HMASK;
        const float2 v = *reinterpret_cast<const float2*>(
            emb + (((size_t)l << 19) + h) * 2);
        __half2 hv = __floats2half2_rn(v.x, v.y);
        dense[j] = *reinterpret_cast<uint32_t*>(&hv);
    }
}

// ---------------- shared helpers ----------------

struct PointCtx { float nx, ny, nz; bool valid; };

__device__ __forceinline__ PointCtx make_ctx(const float* __restrict__ xyz, int pt, int B,
                                             float mn0, float mn1, float mn2,
                                             float inv0, float inv1, float inv2)
{
    PointCtx P;
    P.nx = P.ny = P.nz = 0.0f;
    P.valid = false;
    if (pt < B) {
        const float x = xyz[3 * pt + 0];
        const float y = xyz[3 * pt + 1];
        const float z = xyz[3 * pt + 2];
        P.nx = (x - mn0) * inv0;
        P.ny = (y - mn1) * inv1;
        P.nz = (z - mn2) * inv2;
        P.valid = (P.nx >= 0.0f) && (P.nx <= 1.0f) &&
                  (P.ny >= 0.0f) && (P.ny <= 1.0f) &&
                  (P.nz >= 0.0f) && (P.nz <= 1.0f);
    }
    return P;
}

struct C8 { uint32_t idx[8]; float w[8]; };

__device__ __forceinline__ void frac_setup(const PointCtx& P, int r,
                                           int& fx, int& fy, int& fz,
                                           float& wx0, float& wx1,
                                           float& wy0, float& wy1,
                                           float& wz0, float& wz1)
{
    const float rm1 = (float)(r - 1);
    const float px = P.nx * rm1, py = P.ny * rm1, pz = P.nz * rm1;
    fx = (int)floorf(px); fx = min(max(fx, 0), r - 2);
    fy = (int)floorf(py); fy = min(max(fy, 0), r - 2);
    fz = (int)floorf(pz); fz = min(max(fz, 0), r - 2);
    wx1 = px - (float)fx; wx0 = 1.0f - wx1;
    wy1 = py - (float)fy; wy0 = 1.0f - wy1;
    wz1 = pz - (float)fz; wz0 = 1.0f - wz1;
}

__device__ __forceinline__ C8 mk_hash(const PointCtx& P, int r)
{
    int fx, fy, fz; float wx0, wx1, wy0, wy1, wz0, wz1;
    frac_setup(P, r, fx, fy, fz, wx0, wx1, wy0, wy1, wz0, wz1);
    const uint32_t hx0 = (uint32_t)fx,        hx1 = hx0 + 1u;
    const uint32_t hy0 = (uint32_t)fy * P1,   hy1 = hy0 + P1;
    const uint32_t hz0 = (uint32_t)fz * P2,   hz1 = hz0 + P2;
    C8 c;
    #pragma unroll
    for (int k = 0; k < 8; ++k) {
        c.idx[k] = (((k & 1) ? hx1 : hx0) ^
                    ((k & 2) ? hy1 : hy0) ^
                    ((k & 4) ? hz1 : hz0)) & HMASK;
        c.w[k] = ((k & 1) ? wx1 : wx0) * ((k & 2) ? wy1 : wy0) * ((k & 4) ? wz1 : wz0);
    }
    return c;
}

__device__ __forceinline__ C8 mk_dense(const PointCtx& P, int r, uint32_t off)
{
    int fx, fy, fz; float wx0, wx1, wy0, wy1, wz0, wz1;
    frac_setup(P, r, fx, fy, fz, wx0, wx1, wy0, wy1, wz0, wz1);
    const uint32_t base = off + (uint32_t)(fx + fy * r + fz * r * r);
    C8 c;
    #pragma unroll
    for (int k = 0; k < 8; ++k) {
        c.idx[k] = base + (uint32_t)((k & 1) + ((k & 2) ? r : 0) + ((k & 4) ? r * r : 0));
        c.w[k] = ((k & 1) ? wx1 : wx0) * ((k & 2) ? wy1 : wy0) * ((k & 4) ? wz1 : wz0);
    }
    return c;
}

__device__ __forceinline__ float2 accum8(const C8& c, const uint32_t* e, bool valid)
{
    float a = 0.0f, b = 0.0f;
    #pragma unroll
    for (int k = 0; k < 8; ++k) {
        const float2 f = __half22float2(*reinterpret_cast<const __half2*>(&e[k]));
        a = fmaf(c.w[k], f.x, a);
        b = fmaf(c.w[k], f.y, b);
    }
    float2 o;
    o.x = valid ? a : 0.0f;
    o.y = valid ? b : 0.0f;
    return o;
}

__device__ __forceinline__ void nt_store_f2h(uint32_t* p, float2 v)
{
    __half2 h = __floats2half2_rn(v.x, v.y);
    __builtin_nontemporal_store(*reinterpret_cast<uint32_t*>(&h), p);
}

// ---------------- mega gather: 12 level-major segments in ONE dispatch ----------------
// seg 0       : dense levels 0-4
// seg 1       : dense level 5
// seg 2..11   : hash levels 6..15
__global__ __launch_bounds__(BLOCK, 4) void gather_mega_kernel(
    const float* __restrict__ xyz,
    const uint32_t* __restrict__ tab16,
    const uint32_t* __restrict__ dense,
    const float* __restrict__ minv,
    const float* __restrict__ maxv,
    uint32_t* __restrict__ slab,
    int B, int blocks2)
{
    constexpr int HRES[10] = {111, 154, 212, 294, 406, 561, 776, 1072, 1482, 2048};

    const int seg = blockIdx.x / blocks2;
    const int blk = blockIdx.x - seg * blocks2;

    const int t = threadIdx.x;
    const int p0 = blk * (NPT * BLOCK) + t;
    const int p1 = p0 + BLOCK;

    const float mn0 = minv[0], mn1 = minv[1], mn2 = minv[2];
    const float inv0 = 1.0f / (maxv[0] - mn0);
    const float inv1 = 1.0f / (maxv[1] - mn1);
    const float inv2 = 1.0f / (maxv[2] - mn2);

    const PointCtx A  = make_ctx(xyz, p0, B, mn0, mn1, mn2, inv0, inv1, inv2);
    const PointCtx Bc = make_ctx(xyz, p1, B, mn0, mn1, mn2, inv0, inv1, inv2);

    if (seg == 0) {
        #pragma unroll
        for (int l = 0; l < 5; ++l) {
            const C8 c0 = mk_dense(A,  DRES(l), DOFF(l));
            const C8 c1 = mk_dense(Bc, DRES(l), DOFF(l));
            uint32_t e0[8], e1[8];
            #pragma unroll
            for (int k = 0; k < 8; ++k) e0[k] = dense[c0.idx[k]];
            #pragma unroll
            for (int k = 0; k < 8; ++k) e1[k] = dense[c1.idx[k]];
            const float2 o0 = accum8(c0, e0, A.valid);
            const float2 o1 = accum8(c1, e1, Bc.valid);
            if (p0 < B) nt_store_f2h(&slab[(size_t)l * B + p0], o0);
            if (p1 < B) nt_store_f2h(&slab[(size_t)l * B + p1], o1);
        }
    } else if (seg == 1) {
        const C8 c0 = mk_dense(A,  DRES(5), DOFF(5));
        const C8 c1 = mk_dense(Bc, DRES(5), DOFF(5));
        uint32_t e0[8], e1[8];
        #pragma unroll
        for (int k = 0; k < 8; ++k) e0[k] = dense[c0.idx[k]];
        #pragma unroll
        for (int k = 0; k < 8; ++k) e1[k] = dense[c1.idx[k]];
        const float2 o0 = accum8(c0, e0, A.valid);
        const float2 o1 = accum8(c1, e1, Bc.valid);
        if (p0 < B) nt_store_f2h(&slab[(size_t)5 * B + p0], o0);
        if (p1 < B) nt_store_f2h(&slab[(size_t)5 * B + p1], o1);
    } else {
        const int l = seg + 4;                    // 6..15
        const int r = HRES[seg - 2];
        const uint32_t* __restrict__ lt = tab16 + ((size_t)(l - 6) << 19);
        const C8 c0 = mk_hash(A,  r);
        const C8 c1 = mk_hash(Bc, r);
        uint32_t e0[8], e1[8];
        #pragma unroll
        for (int k = 0; k < 8; ++k) e0[k] = lt[c0.idx[k]];
        #pragma unroll
        for (int k = 0; k < 8; ++k) e1[k] = lt[c1.idx[k]];
        const float2 o0 = accum8(c0, e0, A.valid);
        const float2 o1 = accum8(c1, e1, Bc.valid);
        if (p0 < B) nt_store_f2h(&slab[(size_t)l * B + p0], o0);
        if (p1 < B) nt_store_f2h(&slab[(size_t)l * B + p1], o1);
    }
}

// ---------------- final transpose: slab[16][B] (f16x2) -> out[B][32] (f32) ----------------
__global__ __launch_bounds__(BLOCK) void transpose_kernel(
    const uint32_t* __restrict__ slab,
    float* __restrict__ out,
    int B)
{
    __shared__ float s[32][BLOCK + 1];
    const int t = threadIdx.x;
    const int pt = blockIdx.x * BLOCK + t;

    #pragma unroll
    for (int l = 0; l < NLEVELS; ++l) {
        float2 v = make_float2(0.0f, 0.0f);
        if (pt < B) {
            const uint32_t bits = __builtin_nontemporal_load(&slab[(size_t)l * B + pt]);
            v = __half22float2(*reinterpret_cast<const __half2*>(&bits));
        }
        s[2 * l + 0][t] = v.x;
        s[2 * l + 1][t] = v.y;
    }
    __syncthreads();

    const size_t chunk = (size_t)blockIdx.x * (BLOCK * 32);
    const size_t total = (size_t)B * 32;
    #pragma unroll
    for (int k = 0; k < 32; ++k) {
        const int flat = k * BLOCK + t;
        const int p = flat >> 5;
        const int c = flat & 31;
        const size_t g = chunk + (size_t)flat;
        if (g < total) __builtin_nontemporal_store(s[c][p], &out[g]);
    }
}

// ---------------- fallback: single fused f32 kernel ----------------
__global__ __launch_bounds__(BLOCK) void hashgrid_fused_kernel(
    const float* __restrict__ xyz,
    const float* __restrict__ emb,
    const float* __restrict__ minv,
    const float* __restrict__ maxv,
    float* __restrict__ out,
    int B)
{
    constexpr int RES[NLEVELS] = {16, 22, 30, 42, 58, 80, 111, 154,
                                  212, 294, 406, 561, 776, 1072, 1482, 2048};
    __shared__ float s[32][BLOCK + 1];
    const int t = threadIdx.x;
    const int pt = blockIdx.x * BLOCK + t;

    const float mn0 = minv[0], mn1 = minv[1], mn2 = minv[2];
    const float inv0 = 1.0f / (maxv[0] - mn0);
    const float inv1 = 1.0f / (maxv[1] - mn1);
    const float inv2 = 1.0f / (maxv[2] - mn2);

    const PointCtx P = make_ctx(xyz, pt, B, mn0, mn1, mn2, inv0, inv1, inv2);

    #pragma unroll
    for (int l = 0; l < NLEVELS; ++l) {
        const C8 c = mk_hash(P, RES[l]);
        const float* __restrict__ lemb = emb + ((size_t)l << 20);
        float acc0 = 0.0f, acc1 = 0.0f;
        #pragma unroll
        for (int k = 0; k < 8; ++k) {
            const float2 f = *reinterpret_cast<const float2*>(
                lemb + ((size_t)c.idx[k] << 1));
            acc0 = fmaf(c.w[k], f.x, acc0);
            acc1 = fmaf(c.w[k], f.y, acc1);
        }
        s[2 * l + 0][t] = P.valid ? acc0 : 0.0f;
        s[2 * l + 1][t] = P.valid ? acc1 : 0.0f;
    }
    __syncthreads();
    const size_t chunk = (size_t)blockIdx.x * (BLOCK * 32);
    const size_t total = (size_t)B * 32;
    #pragma unroll
    for (int k = 0; k < 32; ++k) {
        const int flat = k * BLOCK + t;
        const int p = flat >> 5;
        const int c = flat & 31;
        const size_t g = chunk + (size_t)flat;
        if (g < total) out[g] = s[c][p];
    }
}

extern "C" void kernel_launch(void* const* d_in, const int* in_sizes, int n_in,
                              void* d_out, int out_size, void* d_ws, size_t ws_size,
                              hipStream_t stream) {
    const float* xyz = (const float*)d_in[0];
    const float* emb = (const float*)d_in[1];
    const float* mn  = (const float*)d_in[2];
    const float* mx  = (const float*)d_in[3];
    float* out = (float*)d_out;

    const int B = in_sizes[0] / 3;
    const int blocks1 = (B + BLOCK - 1) / BLOCK;
    const int blocks2 = (B + NPT * BLOCK - 1) / (NPT * BLOCK);

    const size_t slab_bytes = (size_t)NLEVELS * (size_t)B * 4;
    const size_t ws_needed = slab_bytes + HASH16_BYTES + DENSE_BYTES;

    if (ws_size >= ws_needed) {
        uint32_t* slab  = (uint32_t*)d_ws;
        uint32_t* tab16 = (uint32_t*)((char*)d_ws + slab_bytes);
        uint32_t* dense = (uint32_t*)((char*)d_ws + slab_bytes + HASH16_BYTES);

        hipLaunchKernelGGL(prep_kernel,
                           dim3((PREP_TOTAL + BLOCK - 1) / BLOCK), dim3(BLOCK),
                           0, stream, emb, tab16, dense);

        hipLaunchKernelGGL(gather_mega_kernel, dim3(12 * blocks2), dim3(BLOCK), 0, stream,
                           xyz, tab16, dense, mn, mx, slab, B, blocks2);

        hipLaunchKernelGGL(transpose_kernel, dim3(blocks1), dim3(BLOCK), 0, stream,
                           slab, out, B);
    } else {
        hipLaunchKernelGGL(hashgrid_fused_kernel, dim3(blocks1), dim3(BLOCK), 0, stream,
                           xyz, emb, mn, mx, out, B);
    }
}